// Round 1
// 293.209 us; speedup vs baseline: 1.1267x; 1.1267x over previous
//
#include <hip/hip_runtime.h>
#include <hip/hip_bf16.h>
#include <cstdint>

typedef unsigned short u16;
typedef __attribute__((ext_vector_type(8))) short bf16x8;
typedef __attribute__((ext_vector_type(4))) float f32x4;

#define BATCH 4
#define CDIM 256
#define NTOK 4096   // H*W

__device__ inline float fexp2(float x) { return __builtin_amdgcn_exp2f(x); }

__device__ inline u16 f2bf(float f) {
  union { float f; uint32_t u; } un; un.f = f;
  uint32_t u = un.u;
  u += 0x7fffu + ((u >> 16) & 1u);
  return (u16)(u >> 16);
}
__device__ inline float bf2f(u16 h) {
  union { uint32_t u; float f; } un; un.u = ((uint32_t)h) << 16; return un.f;
}

__device__ inline void gload_lds16(const u16* g, u16* l) {
  __builtin_amdgcn_global_load_lds((const __attribute__((address_space(1))) void*)g,
                                   (__attribute__((address_space(3))) void*)l, 16, 0, 0);
}

// ---------------------------------------------------------------------------
// LayerNorm: x [B, C, N] -> xn bf16 [B*N, C]
// ---------------------------------------------------------------------------
__global__ __launch_bounds__(256) void ln_kernel(const float* __restrict__ x,
                                                 const float* __restrict__ gamma,
                                                 const float* __restrict__ beta,
                                                 u16* __restrict__ xn) {
  __shared__ float tile[CDIM][33];
  __shared__ float reds[8][32];
  __shared__ float reds2[8][32];
  __shared__ float mu_s[32], rs_s[32];

  int b  = blockIdx.x >> 7;
  int n0 = (blockIdx.x & 127) * 32;
  const float* xb = x + (size_t)b * CDIM * NTOK;

  int t = threadIdx.x & 31;
  int g = threadIdx.x >> 5;

  for (int c = g; c < CDIM; c += 8)
    tile[c][t] = xb[(size_t)c * NTOK + n0 + t];
  __syncthreads();

  float s = 0.f, s2 = 0.f;
  for (int c = g * 32; c < g * 32 + 32; ++c) {
    float v = tile[c][t];
    s += v; s2 += v * v;
  }
  reds[g][t] = s; reds2[g][t] = s2;
  __syncthreads();
  if (threadIdx.x < 32) {
    float ts = 0.f, ts2 = 0.f;
    for (int gg = 0; gg < 8; ++gg) { ts += reds[gg][threadIdx.x]; ts2 += reds2[gg][threadIdx.x]; }
    float mu = ts / CDIM;
    float var = ts2 / CDIM - mu * mu;
    mu_s[threadIdx.x] = mu;
    rs_s[threadIdx.x] = rsqrtf(var + 1e-5f);
  }
  __syncthreads();

  int c = threadIdx.x;
  float gam = gamma[c], bet = beta[c];
  u16* out = xn + ((size_t)b * NTOK + n0) * CDIM;
  for (int tt = 0; tt < 32; ++tt) {
    float v = tile[c][tt];
    float y = (v - mu_s[tt]) * rs_s[tt] * gam + bet;
    out[(size_t)tt * CDIM + c] = f2bf(y);
  }
}

// ---------------------------------------------------------------------------
// W [K, Cout] fp32 -> WT bf16 [Cout, K], optional scale (log2e for Wq)
// ---------------------------------------------------------------------------
__global__ __launch_bounds__(256) void wt_kernel(const float* __restrict__ W,
                                                 u16* __restrict__ WT,
                                                 float scale) {
  __shared__ float tile[32][33];
  int i0 = blockIdx.y * 32;
  int j0 = blockIdx.x * 32;
  int tx = threadIdx.x, ty = threadIdx.y;
  for (int r = ty; r < 32; r += 8)
    tile[r][tx] = W[(size_t)(i0 + r) * CDIM + j0 + tx];
  __syncthreads();
  for (int r = ty; r < 32; r += 8)
    WT[(size_t)(j0 + r) * CDIM + i0 + tx] = f2bf(tile[tx][r] * scale);
}

// ---------------------------------------------------------------------------
// Fused QKV projection: A = xn [16384,256], B3 = stacked [WqT;WkT;WvT]
// [768,256]. One block = 128 m x 64 n; n-range selects output:
//   n<256 -> Qb row-major | n<512 -> Kb row-major | else -> VT transposed.
// ---------------------------------------------------------------------------
__global__ __launch_bounds__(256) void qkv_kernel(const u16* __restrict__ A,
                                                  const u16* __restrict__ B3,
                                                  u16* __restrict__ Qb,
                                                  u16* __restrict__ Kb,
                                                  u16* __restrict__ VT) {
  constexpr int BM = 128, BN = 64, BK = 32;
  __shared__ u16 shA[BM][BK + 8];
  __shared__ u16 shB[BN][BK + 8];

  int m0 = blockIdx.y * BM;
  int n0 = blockIdx.x * BN;

  int tid  = threadIdx.x;
  int lane = tid & 63;
  int wave = tid >> 6;
  int wm = wave >> 1, wn = wave & 1;
  int col  = lane & 15;
  int quad = lane >> 4;

  f32x4 acc[4][2];
#pragma unroll
  for (int i = 0; i < 4; ++i)
#pragma unroll
    for (int j = 0; j < 2; ++j) acc[i][j] = (f32x4){0.f, 0.f, 0.f, 0.f};

  for (int kb = 0; kb < CDIM; kb += BK) {
    __syncthreads();
#pragma unroll
    for (int c = tid; c < BM * BK / 8; c += 256) {
      int row = c >> 2, kc = c & 3;
      *(uint4*)&shA[row][kc * 8] = *(const uint4*)&A[(size_t)(m0 + row) * CDIM + kb + kc * 8];
    }
#pragma unroll
    for (int c = tid; c < BN * BK / 8; c += 256) {
      int row = c >> 2, kc = c & 3;
      *(uint4*)&shB[row][kc * 8] = *(const uint4*)&B3[(size_t)(n0 + row) * CDIM + kb + kc * 8];
    }
    __syncthreads();

    bf16x8 af[4], bfv[2];
#pragma unroll
    for (int i = 0; i < 4; ++i)
      af[i] = *(const bf16x8*)&shA[wm * 64 + i * 16 + col][quad * 8];
#pragma unroll
    for (int j = 0; j < 2; ++j)
      bfv[j] = *(const bf16x8*)&shB[wn * 32 + j * 16 + col][quad * 8];
#pragma unroll
    for (int i = 0; i < 4; ++i)
#pragma unroll
      for (int j = 0; j < 2; ++j)
        acc[i][j] = __builtin_amdgcn_mfma_f32_16x16x32_bf16(af[i], bfv[j], acc[i][j], 0, 0, 0);
  }

  int mode = n0 >> 8;   // 0:Q 1:K 2:V (block-uniform)
  int r0 = quad * 4;
#pragma unroll
  for (int i = 0; i < 4; ++i) {
    int mbase = m0 + wm * 64 + i * 16 + r0;
#pragma unroll
    for (int j = 0; j < 2; ++j) {
      int n = n0 + wn * 32 + j * 16 + col;
#pragma unroll
      for (int r = 0; r < 4; ++r) {
        int m = mbase + r;
        float v = acc[i][j][r];
        if (mode == 0) {
          Qb[(size_t)m * CDIM + n] = f2bf(v);
        } else if (mode == 1) {
          Kb[(size_t)m * CDIM + (n - 256)] = f2bf(v);
        } else {
          int cv = n - 512, bb = m >> 12, nt = m & 4095;
          VT[((size_t)bb * CDIM + cv) * NTOK + nt] = f2bf(v);
        }
      }
    }
  }
}

// ---------------------------------------------------------------------------
// Fused attention, TWO-PASS exact softmax + C-split (R8 structure) with:
//  - exp2 domain (Q pre-scaled by log2e; relu^2 corrected by ln2^2)
//  - hoisted staging addresses (per-thread swizzled offsets precomputed)
//  - pass-1 lazy rescale (__any skip when no row max moved)
//  - pass-2 key-split S: the two h-waves of a q-group each compute HALF the
//    keys' S/P (8 MFMAs, 4 exp2/f2bf per lane), share P via group LDS buffer.
//    Handoff barrier is a raw s_barrier with lgkmcnt-only drain so prefetch
//    global_load_lds stays in flight; the end-of-iter __syncthreads keeps all
//    double-buffer hazards (writer/reader of same buf) fully drained as before.
// ---------------------------------------------------------------------------
__global__ __launch_bounds__(256, 2) void fa_kernel(const u16* __restrict__ Qg,
                                                    const u16* __restrict__ Kg,
                                                    const u16* __restrict__ Vtg,
                                                    const u16* __restrict__ xng,
                                                    const float* __restrict__ w1p,
                                                    const float* __restrict__ w2p,
                                                    float* __restrict__ outg) {
  // A 32768 | B 32768 | P 5120 | stats 512  = 71168 B
  __shared__ __align__(16) char smem[71168];
  float* otile = (float*)smem;          // epilogue overlay [256][36] f32

  int b  = blockIdx.x & 3;              // XCD swizzle: same XCD -> same batch
  int q0 = (blockIdx.x >> 2) * 32;

  const u16* Q  = Qg  + (size_t)b * NTOK * CDIM;
  const u16* K  = Kg  + (size_t)b * NTOK * CDIM;
  const u16* Vt = Vtg + (size_t)b * NTOK * CDIM;

  int tid  = threadIdx.x;
  int lane = tid & 63;
  int wave = tid >> 6;
  int g = wave >> 1, h = wave & 1;
  int col = lane & 15, quad = lane >> 4;

  u16* Pg = (u16*)(smem + 65536) + g * 640;   // group-shared [16][40] u16

  float e1 = __expf(w1p[0]), e2 = __expf(w2p[0]);
  float a1 = e1 / (e1 + e2), a2 = e2 / (e1 + e2);
  float a2p = a2 * 0.4804530139182014f;   // a2 * ln2^2 (S is in log2e domain)

  // ---- Q A-frags from global (16B contiguous per frag), live both passes --
  bf16x8 aq[8];
#pragma unroll
  for (int kk = 0; kk < 8; ++kk)
    aq[kk] = *(const bf16x8*)&Q[(size_t)(q0 + g * 16 + col) * CDIM + kk * 32 + quad * 8];

  // ---- precomputed per-thread staging offsets (u16 elements) ----
  int koff1[8];
#pragma unroll
  for (int it = 0; it < 8; ++it) {
    int row = it * 8 + (tid >> 5);
    int ch  = (tid & 31) ^ (row & 31);
    koff1[it] = row * CDIM + ch * 8;
  }
  int koff2[4], voff2[4];
#pragma unroll
  for (int it = 0; it < 4; ++it) {
    int row = it * 8 + (tid >> 5);
    int ch  = (tid & 31) ^ row;           // row < 32
    koff2[it] = row * CDIM + ch * 8;
    int vr  = it * 64 + (tid >> 2);
    int vch = (tid & 3) ^ ((vr >> 1) & 3);
    voff2[it] = vr * NTOK + vch * 8;
  }

  // =========================== PASS 1: m, l ================================
  u16* ka = (u16*)smem;            // K tile 64: [64][256] u16 = 32 KB
  u16* kb = ka + 16384;

  auto stage1 = [&](int n1, u16* Kdst) {
    const u16* kgb = K + (size_t)n1 * CDIM;
#pragma unroll
    for (int it = 0; it < 8; ++it)
      gload_lds16(kgb + koff1[it], Kdst + (size_t)(it * 256 + wave * 64) * 8);
  };

  stage1(0, ka);

  float ml[4], ll[4];
#pragma unroll
  for (int r = 0; r < 4; ++r) { ml[r] = -3e38f; ll[r] = 0.f; }

  __syncthreads();

  for (int t = 0; t < 64; ++t) {
    if (t < 63) stage1((t + 1) * 64, kb);

    f32x4 s[2];
#pragma unroll
    for (int j = 0; j < 2; ++j) s[j] = (f32x4){0.f, 0.f, 0.f, 0.f};
#pragma unroll
    for (int kk = 0; kk < 8; ++kk) {
#pragma unroll
      for (int j = 0; j < 2; ++j) {
        int kr = h * 32 + j * 16 + col;
        bf16x8 bk = *(const bf16x8*)&ka[(size_t)kr * 256 + (((kk * 4 + quad) ^ kr) & 31) * 8];
        s[j] = __builtin_amdgcn_mfma_f32_16x16x32_bf16(aq[kk], bk, s[j], 0, 0, 0);
      }
    }
    // per-lane online update (exp2 domain); lazy rescale when max stable
    float mnew[4];
    bool chg = false;
#pragma unroll
    for (int r = 0; r < 4; ++r) {
      float pm = fmaxf(s[0][r], s[1][r]);
      mnew[r] = fmaxf(ml[r], pm);
      chg = chg || (mnew[r] > ml[r]);
    }
    if (__any(chg)) {
#pragma unroll
      for (int r = 0; r < 4; ++r) {
        ll[r] = ll[r] * fexp2(ml[r] - mnew[r]) +
                fexp2(s[0][r] - mnew[r]) + fexp2(s[1][r] - mnew[r]);
        ml[r] = mnew[r];
      }
    } else {
#pragma unroll
      for (int r = 0; r < 4; ++r)
        ll[r] += fexp2(s[0][r] - ml[r]) + fexp2(s[1][r] - ml[r]);
    }
    __syncthreads();
    u16* tk = ka; ka = kb; kb = tk;
  }

  // merge across the 16 cols of this wave (4 shuffle steps, once)
#pragma unroll
  for (int off = 1; off < 16; off <<= 1)
#pragma unroll
    for (int r = 0; r < 4; ++r) {
      float mo = __shfl_xor(ml[r], off);
      float lo = __shfl_xor(ll[r], off);
      float mn = fmaxf(ml[r], mo);
      ll[r] = ll[r] * fexp2(ml[r] - mn) + lo * fexp2(mo - mn);
      ml[r] = mn;
    }
  // merge the two key-halves (h waves of this group) via LDS, once
  float* mbuf = (float*)(smem + 70656);   // [2g][2h][16]
  float* lbuf = mbuf + 64;
  if (col == 0) {
#pragma unroll
    for (int r = 0; r < 4; ++r) {
      mbuf[(g * 2 + h) * 16 + quad * 4 + r] = ml[r];
      lbuf[(g * 2 + h) * 16 + quad * 4 + r] = ll[r];
    }
  }
  __syncthreads();
  float mf[4], c1[4];
#pragma unroll
  for (int r = 0; r < 4; ++r) {
    float mo = mbuf[(g * 2 + (1 - h)) * 16 + quad * 4 + r];
    float lo = lbuf[(g * 2 + (1 - h)) * 16 + quad * 4 + r];
    float mn = fmaxf(ml[r], mo);
    float lf = ll[r] * fexp2(ml[r] - mn) + lo * fexp2(mo - mn);
    mf[r] = mn;
    c1[r] = a1 / lf;
  }

  // =========================== PASS 2: P, O ================================
  u16* k2a = (u16*)smem;                 // [32][256] u16 = 16 KB
  u16* k2b = k2a + 8192;
  u16* v2a = (u16*)(smem + 32768);       // [256][32] u16 = 16 KB
  u16* v2b = v2a + 8192;

  auto stage2 = [&](int n1, u16* Kdst, u16* Vdst) {
    const u16* kgb = K + (size_t)n1 * CDIM;
    const u16* vgb = Vt + n1;
#pragma unroll
    for (int it = 0; it < 4; ++it)
      gload_lds16(kgb + koff2[it], Kdst + (size_t)(it * 256 + wave * 64) * 8);
#pragma unroll
    for (int it = 0; it < 4; ++it)
      gload_lds16(vgb + voff2[it], Vdst + (size_t)(it * 256 + wave * 64) * 8);
  };

  f32x4 o[8];
#pragma unroll
  for (int j = 0; j < 8; ++j) o[j] = (f32x4){0.f, 0.f, 0.f, 0.f};

  stage2(0, k2a, v2a);
  __syncthreads();

  for (int t = 0; t < 128; ++t) {
    // (A) issue next-tile prefetch; stays in flight across the raw barrier,
    // drained by the end-of-iter __syncthreads.
    if (t < 127) stage2((t + 1) * 32, ((t + 1) & 1) ? k2b : k2a,
                        ((t + 1) & 1) ? v2b : v2a);
    const u16* ks = (t & 1) ? k2b : k2a;
    const u16* vs = (t & 1) ? v2b : v2a;

    // S for THIS wave's key half only (16 keys -> 8 MFMAs)
    f32x4 s = (f32x4){0.f, 0.f, 0.f, 0.f};
    int kr = h * 16 + col;
#pragma unroll
    for (int kk = 0; kk < 8; ++kk) {
      bf16x8 bk = *(const bf16x8*)&ks[(size_t)kr * 256 + (((kk * 4 + quad) ^ kr) & 31) * 8];
      s = __builtin_amdgcn_mfma_f32_16x16x32_bf16(aq[kk], bk, s, 0, 0, 0);
    }

    // combined P = c1*exp2(S-m) + a2p*relu(S)^2 for this key half (4 vals)
#pragma unroll
    for (int r = 0; r < 4; ++r) {
      float sv = s[r];
      float rl = sv > 0.f ? sv * sv : 0.f;
      float p = c1[r] * fexp2(sv - mf[r]) + a2p * rl;
      Pg[(size_t)(quad * 4 + r) * 40 + h * 16 + col] = f2bf(p);
    }

    // P handoff: drain LDS writes only (NOT vmcnt) + raw barrier
    asm volatile("s_waitcnt lgkmcnt(0)" ::: "memory");
    __builtin_amdgcn_s_barrier();
    __builtin_amdgcn_sched_barrier(0);

    // (B) PV over this wave's 128 channels, full 32 keys from shared P
    bf16x8 pa = *(const bf16x8*)&Pg[(size_t)col * 40 + quad * 8];
#pragma unroll
    for (int j = 0; j < 8; ++j) {
      int vr = h * 128 + j * 16 + col;
      bf16x8 bv = *(const bf16x8*)&vs[(size_t)vr * 32 + (quad ^ ((vr >> 1) & 3)) * 8];
      o[j] = __builtin_amdgcn_mfma_f32_16x16x32_bf16(pa, bv, o[j], 0, 0, 0);
    }

    __syncthreads();   // prefetch landed + all waves done with current bufs + P
  }

  // ---- epilogue: residual + transpose to [c][n] ----
#pragma unroll
  for (int j = 0; j < 8; ++j) {
    int c = h * 128 + j * 16 + col;
    float4 v4;
    float* vv = (float*)&v4;
#pragma unroll
    for (int r = 0; r < 4; ++r) {
      int row = g * 16 + quad * 4 + r;
      vv[r] = o[j][r] + bf2f(xng[((size_t)b * NTOK + q0 + row) * CDIM + c]);
    }
    *(float4*)&otile[(size_t)c * 36 + g * 16 + quad * 4] = v4;
  }
  __syncthreads();

#pragma unroll
  for (int it = 0; it < 8; ++it) {
    int c  = it * 32 + (tid >> 3);
    int ch = tid & 7;
    *(float4*)&outg[((size_t)b * CDIM + c) * NTOK + q0 + ch * 4] =
        *(const float4*)&otile[(size_t)c * 36 + ch * 4];
  }
}

// ---------------------------------------------------------------------------
extern "C" void kernel_launch(void* const* d_in, const int* in_sizes, int n_in,
                              void* d_out, int out_size, void* d_ws, size_t ws_size,
                              hipStream_t stream) {
  const float* x     = (const float*)d_in[0];
  const float* gamma = (const float*)d_in[1];
  const float* beta  = (const float*)d_in[2];
  const float* Wq    = (const float*)d_in[3];
  const float* Wk    = (const float*)d_in[4];
  const float* Wv    = (const float*)d_in[5];
  const float* w1    = (const float*)d_in[6];
  const float* w2    = (const float*)d_in[7];
  float* out = (float*)d_out;

  char* ws = (char*)d_ws;
  size_t off = 0;
  u16* xn  = (u16*)(ws + off); off += (size_t)BATCH * NTOK * CDIM * 2;
  u16* WT3 = (u16*)(ws + off); off += (size_t)3 * CDIM * CDIM * 2;   // [768][256]
  u16* Qb  = (u16*)(ws + off); off += (size_t)BATCH * NTOK * CDIM * 2;
  u16* Kb  = (u16*)(ws + off); off += (size_t)BATCH * NTOK * CDIM * 2;
  u16* VT  = (u16*)(ws + off); off += (size_t)BATCH * NTOK * CDIM * 2;  // [b][c][n]

  const float LOG2E = 1.4426950408889634f;

  // 1) LayerNorm -> xn bf16 [B*N, C]
  ln_kernel<<<dim3(BATCH * (NTOK / 32)), 256, 0, stream>>>(x, gamma, beta, xn);

  // 2) stacked transposed weights (Wq pre-scaled by log2e -> exp2-domain S)
  wt_kernel<<<dim3(8, 8), dim3(32, 8), 0, stream>>>(Wq, WT3, LOG2E);
  wt_kernel<<<dim3(8, 8), dim3(32, 8), 0, stream>>>(Wk, WT3 + 256 * 256, 1.0f);
  wt_kernel<<<dim3(8, 8), dim3(32, 8), 0, stream>>>(Wv, WT3 + 512 * 256, 1.0f);

  // 3) fused Q/K/V projection (one launch)
  qkv_kernel<<<dim3(12, 128), 256, 0, stream>>>(xn, WT3, Qb, Kb, VT);

  // 4) fused attention (two-pass) + mix + residual + transpose
  fa_kernel<<<dim3(512), 256, 0, stream>>>(Qb, Kb, VT, xn, w1, w2, out);
}